// Round 15
// baseline (273.174 us; speedup 1.0000x reference)
//
#include <hip/hip_runtime.h>
#include <stdint.h>

typedef unsigned short u16;
typedef __attribute__((ext_vector_type(8))) short bh8;   // 8 bf16 = 4 VGPR
typedef __attribute__((ext_vector_type(4))) float f4;    // MFMA acc

#define LOG2E 1.44269504088896f
#define QSCALE 0.18033688f   // 0.125 * log2(e), folded into Q at GEMM1 epilogue

__device__ inline u16 f2bf(float f) {
  union { float f; uint32_t u; } c; c.f = f;
  uint32_t u = c.u;
  return (u16)((u + 0x7fffu + ((u >> 16) & 1u)) >> 16);  // RNE
}

__device__ inline float fast_exp2(float x) {
#if __has_builtin(__builtin_amdgcn_exp2f)
  return __builtin_amdgcn_exp2f(x);
#else
  return exp2f(x);
#endif
}

// pack hi16 of two u32s into one u32: dst = (a>>16) | (b & 0xFFFF0000).
// v_perm_b32 byte-extract: sel bytes 0-3 pick from S1 (=a), 4-7 from S0 (=b).
// sel 0x07060302: b0=a.b2, b1=a.b3, b2=b.b2, b3=b.b3 -> BIT-IDENTICAL to the
// masked shift-or chain it replaces (1 instr vs 3-4).
__device__ inline uint32_t pack_hi16(uint32_t a, uint32_t b) {
#if __has_builtin(__builtin_amdgcn_perm)
  return __builtin_amdgcn_perm(b, a, 0x07060302u);
#else
  return (a >> 16) | (b & 0xFFFF0000u);
#endif
}

#if __has_builtin(__builtin_amdgcn_global_load_lds)
#define GLD16(gp, lp) __builtin_amdgcn_global_load_lds( \
    (const __attribute__((address_space(1))) void*)(gp), \
    (__attribute__((address_space(3))) void*)(lp), 16, 0, 0)
#else
#define GLD16(gp, lp) do { *(bh8*)(lp) = *(const bh8*)(gp); } while (0)
#endif

#if __has_builtin(__builtin_amdgcn_s_setprio)
#define SETPRIO(n) __builtin_amdgcn_s_setprio(n)
#else
#define SETPRIO(n) do {} while (0)
#endif

// ---------------- merged prep: x cvt + both weight transposes ----------------------
// Blocks [0,8192): x f32->bf16. [8192,11264): w_qkv transpose. [11264,12288): w_out.

__device__ inline void transpose_tile_256(const float* __restrict__ src,
                                          u16* __restrict__ dst, int K, int N,
                                          int k0, int n0, float (*tile)[33]) {
  int tx = threadIdx.x & 31, ty0 = threadIdx.x >> 5;
#pragma unroll
  for (int s = 0; s < 4; ++s) {
    int ty = ty0 + s * 8;
    tile[ty][tx] = src[(size_t)(k0 + ty) * N + n0 + tx];
  }
  __syncthreads();
#pragma unroll
  for (int s = 0; s < 4; ++s) {
    int ty = ty0 + s * 8;
    dst[(size_t)(n0 + ty) * K + k0 + tx] = f2bf(tile[tx][ty]);
  }
}

__global__ __launch_bounds__(256) void prep(const float* __restrict__ x,
                                            u16* __restrict__ xb,
                                            const float* __restrict__ w_qkv,
                                            u16* __restrict__ wqt,
                                            const float* __restrict__ w_out,
                                            u16* __restrict__ wot) {
  __shared__ float tile[32][33];
  const int bid = blockIdx.x;
  if (bid < 8192) {
    int i = bid * 256 + threadIdx.x;
    float4 v = ((const float4*)x)[i];
    ushort4 o;
    o.x = f2bf(v.x); o.y = f2bf(v.y); o.z = f2bf(v.z); o.w = f2bf(v.w);
    ((ushort4*)xb)[i] = o;
  } else if (bid < 8192 + 3072) {
    int t = bid - 8192;                       // w_qkv: N=3072 (96 n-tiles), K=1024
    transpose_tile_256(w_qkv, wqt, 1024, 3072, (t / 96) * 32, (t % 96) * 32, tile);
  } else {
    int t = bid - 11264;                      // w_out: N=1024 (32 n-tiles), K=1024
    transpose_tile_256(w_out, wot, 1024, 1024, (t / 32) * 32, (t % 32) * 32, tile);
  }
}

// ---------------- GEMM mainloop (C = A @ Bt^T), 128x128 tile, BK=64 ----------------
__device__ inline void gemm_mainloop(const u16* __restrict__ A, const u16* __restrict__ Bt,
                                     int K, int m0, int n0,
                                     u16* As, u16* Bs, f4 acc[4][4]) {
  const int tid  = threadIdx.x;
  const int lane = tid & 63;
  const int quad = lane >> 4;
  const int ml   = lane & 15;
  const int wave = tid >> 6;
  const int wm   = (wave >> 1) * 64;
  const int wn   = (wave & 1) * 64;

#pragma unroll 1
  for (int k0 = 0; k0 < K; k0 += 64) {
#pragma unroll
    for (int r = 0; r < 4; ++r) {
      int chunk = r * 256 + tid;
      int row = chunk >> 3, cc = chunk & 7;
      int cg = cc ^ (row & 7);
      GLD16(A + (size_t)(m0 + row) * K + k0 + cg * 8, As + chunk * 8);
    }
#pragma unroll
    for (int r = 0; r < 4; ++r) {
      int chunk = r * 256 + tid;
      int row = chunk >> 3, cc = chunk & 7;
      int cg = cc ^ (row & 7);
      GLD16(Bt + (size_t)(n0 + row) * K + k0 + cg * 8, Bs + chunk * 8);
    }
    __syncthreads();
#pragma unroll
    for (int ks = 0; ks < 2; ++ks) {
      bh8 af[4], bfr[4];
      int cs = (ks * 4 + quad) ^ (ml & 7);
#pragma unroll
      for (int i = 0; i < 4; ++i) {
        int row = wm + i * 16 + ml;
        af[i] = *(const bh8*)(As + (row * 8 + cs) * 8);
      }
#pragma unroll
      for (int j = 0; j < 4; ++j) {
        int row = wn + j * 16 + ml;
        bfr[j] = *(const bh8*)(Bs + (row * 8 + cs) * 8);
      }
#pragma unroll
      for (int i = 0; i < 4; ++i)
#pragma unroll
        for (int j = 0; j < 4; ++j)
          acc[i][j] = __builtin_amdgcn_mfma_f32_16x16x32_bf16(af[i], bfr[j], acc[i][j], 0, 0, 0);
    }
    __syncthreads();
  }
}

// ---------------- GEMM1: qkv = x @ w_qkv + b ----------------
// q scaled by QSCALE; q,k stored [bh][l][d]; V stored DIRECTLY TRANSPOSED [bh][d][l].
// XCD-locality swizzle: xcd = wgid&7, contiguous m-band per XCD.
__global__ __launch_bounds__(256) void gemm_qkv(const u16* __restrict__ xb,
                                                const u16* __restrict__ wqt,
                                                const float* __restrict__ bqkv,
                                                u16* __restrict__ q, u16* __restrict__ k,
                                                u16* __restrict__ v) {
  __shared__ __align__(16) u16 smem[2 * 128 * 64];
  const f4 fzero = {0.f, 0.f, 0.f, 0.f};
  f4 acc[4][4];
#pragma unroll
  for (int i = 0; i < 4; ++i)
#pragma unroll
    for (int j = 0; j < 4; ++j) acc[i][j] = fzero;

  const int wgid = blockIdx.x;                 // 0..1535
  const int xcd = wgid & 7, loc = wgid >> 3;   // loc in [0,192)
  const int mt = xcd * 8 + loc / 24;           // m-tile 0..63
  const int nt = loc % 24;                     // n-tile 0..23
  int m0 = mt * 128, n0 = nt * 128;
  gemm_mainloop(xb, wqt, 1024, m0, n0, smem, smem + 128 * 64, acc);

  const int lane = threadIdx.x & 63, wave = threadIdx.x >> 6;
  const int quad = lane >> 4, ml = lane & 15;
  const int wm = (wave >> 1) * 64, wn = (wave & 1) * 64;
  if (n0 < 2048) {
    u16* dst = (n0 < 1024) ? q : k;
    float scale = (n0 < 1024) ? QSCALE : 1.0f;
#pragma unroll
    for (int j = 0; j < 4; ++j) {
      int nn = n0 + wn + j * 16 + ml;
      int h = (nn >> 6) & 15, d = nn & 63;
      float bias = bqkv[nn];
#pragma unroll
      for (int i = 0; i < 4; ++i) {
#pragma unroll
        for (int r = 0; r < 4; ++r) {
          int tok = m0 + wm + i * 16 + quad * 4 + r;
          int b = tok >> 11, l = tok & 2047;
          int bh = b * 16 + h;
          dst[((size_t)bh * 2048 + l) * 64 + d] = f2bf((acc[i][j][r] + bias) * scale);
        }
      }
    }
  } else {
    // V path: store transposed [bh][d][2048], 8B vector stores
#pragma unroll
    for (int j = 0; j < 4; ++j) {
      int nn = n0 + wn + j * 16 + ml;
      int h = (nn >> 6) & 15, d = nn & 63;
      float bias = bqkv[nn];
#pragma unroll
      for (int i = 0; i < 4; ++i) {
        int tok = m0 + wm + i * 16 + quad * 4;   // r=0 base; +r stays in-batch
        int b = tok >> 11, l = tok & 2047;
        int bh = b * 16 + h;
        ushort4 w;
        w.x = f2bf(acc[i][j][0] + bias);
        w.y = f2bf(acc[i][j][1] + bias);
        w.z = f2bf(acc[i][j][2] + bias);
        w.w = f2bf(acc[i][j][3] + bias);
        *(ushort4*)&v[((size_t)bh * 64 + d) * 2048 + l] = w;
      }
    }
  }
}

// ---------------- GEMM2: out = o @ w_out + b_out (fp32 out), 64x128 tile -----------
// XCD-locality swizzle.
__global__ __launch_bounds__(256) void gemm_out64(const u16* __restrict__ ob,
                                                  const u16* __restrict__ wot,
                                                  const float* __restrict__ bout,
                                                  float* __restrict__ out) {
  __shared__ __align__(16) u16 As[64 * 64];
  __shared__ __align__(16) u16 Bs[128 * 64];
  const int tid  = threadIdx.x;
  const int lane = tid & 63;
  const int quad = lane >> 4;
  const int ml   = lane & 15;
  const int wave = tid >> 6;
  const int wm   = (wave >> 1) * 32;   // 2 wave-rows x 32
  const int wn   = (wave & 1) * 64;    // 2 wave-cols x 64
  const int wgid = blockIdx.x;                  // 0..1023
  const int xcd = wgid & 7, loc = wgid >> 3;    // loc in [0,128)
  const int mt = xcd * 16 + loc / 8;            // m-tile 0..127
  const int nt = loc % 8;                       // n-tile 0..7
  const int m0 = mt * 64, n0 = nt * 128;

  const f4 fzero = {0.f, 0.f, 0.f, 0.f};
  f4 acc[2][4];
#pragma unroll
  for (int i = 0; i < 2; ++i)
#pragma unroll
    for (int j = 0; j < 4; ++j) acc[i][j] = fzero;

  const int srow = tid >> 3, scc = tid & 7;
  const int scg = scc ^ (srow & 7);

#pragma unroll 1
  for (int k0 = 0; k0 < 1024; k0 += 64) {
#pragma unroll
    for (int r = 0; r < 2; ++r) {
      int row = r * 32 + srow;   // [0,64)
      GLD16(ob + (size_t)(m0 + row) * 1024 + k0 + scg * 8, As + (row * 8 + scc) * 8);
    }
#pragma unroll
    for (int r = 0; r < 4; ++r) {
      int row = r * 32 + srow;   // [0,128)
      GLD16(wot + (size_t)(n0 + row) * 1024 + k0 + scg * 8, Bs + (row * 8 + scc) * 8);
    }
    __syncthreads();
#pragma unroll
    for (int ks = 0; ks < 2; ++ks) {
      int cs = (ks * 4 + quad) ^ (ml & 7);
      bh8 af[2], bfr[4];
#pragma unroll
      for (int i = 0; i < 2; ++i)
        af[i] = *(const bh8*)(As + ((wm + i * 16 + ml) * 8 + cs) * 8);
#pragma unroll
      for (int j = 0; j < 4; ++j)
        bfr[j] = *(const bh8*)(Bs + ((wn + j * 16 + ml) * 8 + cs) * 8);
#pragma unroll
      for (int i = 0; i < 2; ++i)
#pragma unroll
        for (int j = 0; j < 4; ++j)
          acc[i][j] = __builtin_amdgcn_mfma_f32_16x16x32_bf16(af[i], bfr[j], acc[i][j], 0, 0, 0);
    }
    __syncthreads();
  }

#pragma unroll
  for (int j = 0; j < 4; ++j) {
    int nn = n0 + wn + j * 16 + ml;
    float bias = bout[nn];
#pragma unroll
    for (int i = 0; i < 2; ++i)
#pragma unroll
      for (int r = 0; r < 4; ++r) {
        int tok = m0 + wm + i * 16 + quad * 4 + r;
        out[(size_t)tok * 1024 + nn] = acc[i][j][r] + bias;
      }
  }
}

// ---------------- flash attention v15: v14 + v_perm byte-extract pack --------------
// v14 proven: 92.2us, 0 conflicts, absmax 4.88e-4. Round-15: the bf16 pack chain
// (add + and + shift + or per value pair) is a byte-extract -> one v_perm_b32 per
// u32 pair via __builtin_amdgcn_perm. Rounding (+0x8000) kept; result is
// BIT-IDENTICAL to v13/v14's pack (selector derived byte-by-byte; absmax must
// stay exactly 4.882812e-4 — any change falsifies the selector semantics).
// Saves ~4-8 VALU ops per 8B granule x 8 granules/tile out of ~830 VALU cyc/tile.
// Conflict history: v10 4.19M -> v11 2.10M (compiler b128-merge) -> v13 0
// (bit1-separated pair). Numerics: half-up pack + ones-MFMA denominator (same
// bf16 P for num and den). v_cvt_pk_bf16_f32 BANNED (failed twice: pack order).
__global__ __launch_bounds__(256, 4) void attn(const u16* __restrict__ q,
                                               const u16* __restrict__ k,
                                               const u16* __restrict__ vt,
                                               u16* __restrict__ o) {
  __shared__ __align__(16) u16 Ks[2][64 * 64];    // row=key, 8 chunks, XOR swizzle
  __shared__ __align__(16) u16 Vs[2][64 * 64];    // row=d,   cols=key, XOR swizzle
  __shared__ __align__(16) u16 Pq[4][16 * 64];    // per-wave P, per-ml 128B regions
  const int bh = blockIdx.x;
  const int b = bh >> 4, h = bh & 15;
  const int tid = threadIdx.x;
  const int wave = tid >> 6, lane = tid & 63;
  const int quad = lane >> 4, ml = lane & 15;
  const int qw = blockIdx.y * 128 + wave * 32;
  const u16* qp = q + (size_t)bh * 2048 * 64;
  const u16* kp = k + (size_t)bh * 2048 * 64;
  const u16* vp = vt + (size_t)bh * 64 * 2048;
  const f4 fzero = {0.f, 0.f, 0.f, 0.f};

  const int mlx = ml & 7;    // XOR bits for Ks/Vs 16B-chunk swizzle

  // ones A-fragment for the li row-sum MFMA (bf16 1.0 in every element)
  bh8 ones;
#pragma unroll
  for (int t = 0; t < 8; ++t) ones[t] = (short)0x3F80;

  // Q fragments: B-operand, rows qw+g*16+ml, 16B contiguous
  bh8 qf[2][2];
#pragma unroll
  for (int g = 0; g < 2; ++g)
#pragma unroll
    for (int ks = 0; ks < 2; ++ks)
      qf[g][ks] = *(const bh8*)&qp[(size_t)(qw + g * 16 + ml) * 64 + ks * 32 + quad * 8];

  f4 oacc[2][4], liacc[2];
#pragma unroll
  for (int g = 0; g < 2; ++g) {
#pragma unroll
    for (int j = 0; j < 4; ++j) oacc[g][j] = fzero;
    liacc[g] = fzero;
  }

  // staging addresses (row/chunk decomposition identical to gemm_mainloop)
  const int srow = tid >> 3, scc = tid & 7;
  const int scg = scc ^ (srow & 7);
  u16* pq = &Pq[wave][ml * 64];   // this lane's 128B region: 16 slots x 8B

  // prologue: stage K+V tile 0 into buffer 0
#pragma unroll
  for (int r = 0; r < 2; ++r) {
    int row = r * 32 + srow;
    GLD16(kp + (size_t)row * 64 + scg * 8, &Ks[0][(row * 8 + scc) * 8]);
    GLD16(vp + (size_t)row * 2048 + scg * 8, &Vs[0][(row * 8 + scc) * 8]);
  }
  __syncthreads();

  int cur = 0;
#pragma unroll 1
  for (int t = 0; t < 32; ++t) {
    // stage next K+V tile into the other buffer (in flight until end-of-tile drain)
    if (t < 31) {
      int ktn = (t + 1) * 64;
#pragma unroll
      for (int r = 0; r < 2; ++r) {
        int row = r * 32 + srow;
        GLD16(kp + (size_t)(ktn + row) * 64 + scg * 8, &Ks[cur ^ 1][(row * 8 + scc) * 8]);
        GLD16(vp + (size_t)row * 2048 + ktn + scg * 8, &Vs[cur ^ 1][(row * 8 + scc) * 8]);
      }
    }

    // S^T = K @ Q^T from LDS: s[g][j][r] = S[q=qw+g*16+ml][kt + 16j + 4quad + r]
    f4 s[2][4];
#pragma unroll
    for (int g = 0; g < 2; ++g)
#pragma unroll
      for (int j = 0; j < 4; ++j) s[g][j] = fzero;
#pragma unroll
    for (int ks = 0; ks < 2; ++ks) {
      int cs = (ks * 4 + quad) ^ mlx;
      bh8 kf[4];
#pragma unroll
      for (int j = 0; j < 4; ++j)
        kf[j] = *(const bh8*)(&Ks[cur][((j * 16 + ml) * 8 + cs) * 8]);
      SETPRIO(1);
#pragma unroll
      for (int j = 0; j < 4; ++j) {
        s[0][j] = __builtin_amdgcn_mfma_f32_16x16x32_bf16(kf[j], qf[0][ks], s[0][j], 0, 0, 0);
        s[1][j] = __builtin_amdgcn_mfma_f32_16x16x32_bf16(kf[j], qf[1][ks], s[1][j], 0, 0, 0);
      }
      SETPRIO(0);
    }

    // two ks-phases: softmax keys [32ks,32ks+32) -> write -> pf read -> PV + li.
    // Pq slots reused across phases (same-wave DS in-order => WAR safe).
#pragma unroll
    for (int ks = 0; ks < 2; ++ks) {
      // p = exp2(s) -> bf16 half-up; pack via v_perm byte-extract (bit-identical)
#pragma unroll
      for (int g = 0; g < 2; ++g) {
#pragma unroll
        for (int jl = 0; jl < 2; ++jl) {
          int j = ks * 2 + jl;
          uint32_t w[4];
#pragma unroll
          for (int r = 0; r < 4; ++r) {
            union { float f; uint32_t u; } c;
            c.f = fast_exp2(s[g][j][r]);
            w[r] = c.u + 0x8000u;
          }
          uint2 pk;
          pk.x = pack_hi16(w[0], w[1]);
          pk.y = pack_hi16(w[2], w[3]);
          // slot: bit0 <- quad&1, bit1 <- quad>>1 (pair-distinction lives in bit1)
          int sl = (g * 8 + jl * 4 + 2 * (quad & 1) + (quad >> 1)) ^ ml;
          *(uint2*)(pq + (sl << 2)) = pk;
        }
      }

      // O^T += V^T @ P^T ; li += 1 @ P^T  (vf from LDS, reused for both groups;
      // pf via two b64 reads 16B apart -> unmergeable, conflict-free)
      int cs = (ks * 4 + quad) ^ mlx;
      bh8 vf[4];
#pragma unroll
      for (int j = 0; j < 4; ++j)
        vf[j] = *(const bh8*)(&Vs[cur][((j * 16 + ml) * 8 + cs) * 8]);
#pragma unroll
      for (int g = 0; g < 2; ++g) {
        int slo = (g * 8 + 4 * (quad >> 1) + (quad & 1)) ^ ml;
        int shi = slo ^ 2;
        uint2 lo = *(const uint2*)(pq + (slo << 2));
        uint2 hi = *(const uint2*)(pq + (shi << 2));
        union { uint32_t u[4]; bh8 v; } pf;
        pf.u[0] = lo.x; pf.u[1] = lo.y; pf.u[2] = hi.x; pf.u[3] = hi.y;
        SETPRIO(1);
#pragma unroll
        for (int j = 0; j < 4; ++j)
          oacc[g][j] = __builtin_amdgcn_mfma_f32_16x16x32_bf16(vf[j], pf.v, oacc[g][j], 0, 0, 0);
        liacc[g] = __builtin_amdgcn_mfma_f32_16x16x32_bf16(ones, pf.v, liacc[g], 0, 0, 0);
        SETPRIO(0);
      }
    }
    __syncthreads();   // drains K/V stage (vmcnt) + all LDS reads of buf[cur]
    cur ^= 1;
  }

  // li[g] came through the same bf16 P as the numerator; every acc row holds the
  // full row-sum for q=qw+g*16+ml (ones x P^T), so no cross-lane reduction needed.
#pragma unroll
  for (int g = 0; g < 2; ++g) {
    float inv = 1.0f / liacc[g][0];
    // store o as (b, l, h, d) bf16; lane holds q=qw+g*16+ml, d=16j+4quad+r
    size_t obase = (((size_t)b * 2048 + qw + g * 16 + ml) * 16 + h) * 64;
#pragma unroll
    for (int j = 0; j < 4; ++j) {
      ushort4 w;
      w.x = f2bf(oacc[g][j][0] * inv);
      w.y = f2bf(oacc[g][j][1] * inv);
      w.z = f2bf(oacc[g][j][2] * inv);
      w.w = f2bf(oacc[g][j][3] * inv);
      *(ushort4*)(o + obase + j * 16 + quad * 4) = w;
    }
  }
}

// ---------------- launch ----------------
// prep = merged cvt + weight transposes. gemm_qkv writes vt DIRECTLY into vb
// (transposed); attn writes o into xb (dead after gemm_qkv); gemm_out64 reads xb.
// GEMM grids 1-D with in-kernel XCD decomposition.

extern "C" void kernel_launch(void* const* d_in, const int* in_sizes, int n_in,
                              void* d_out, int out_size, void* d_ws, size_t ws_size,
                              hipStream_t stream) {
  const float* x     = (const float*)d_in[0];
  const float* w_qkv = (const float*)d_in[1];
  const float* b_qkv = (const float*)d_in[2];
  const float* w_out = (const float*)d_in[3];
  const float* b_out = (const float*)d_in[4];
  float* out = (float*)d_out;

  u16* ws  = (u16*)d_ws;
  u16* xb  = ws;                                  // 8192*1024 (o reuses after gemm_qkv)
  u16* wqt = xb + (size_t)8192 * 1024;            // 3072*1024
  u16* wot = wqt + (size_t)3072 * 1024;           // 1024*1024
  u16* qb  = wot + (size_t)1024 * 1024;           // 64*2048*64
  u16* kb  = qb + (size_t)64 * 2048 * 64;
  u16* vb  = kb + (size_t)64 * 2048 * 64;         // vt [bh][d][l] (written directly)
  u16* ob  = xb;   // xb dead after gemm_qkv

  prep<<<12288, 256, 0, stream>>>(x, xb, w_qkv, wqt, w_out, wot);
  gemm_qkv<<<1536, 256, 0, stream>>>(xb, wqt, b_qkv, qb, kb, vb);
  attn<<<dim3(64, 16), 256, 0, stream>>>(qb, kb, vb, ob);
  gemm_out64<<<1024, 256, 0, stream>>>(ob, wot, b_out, out);
}

// Round 16
// 263.557 us; speedup vs baseline: 1.0365x; 1.0365x over previous
//
#include <hip/hip_runtime.h>
#include <stdint.h>

typedef unsigned short u16;
typedef __attribute__((ext_vector_type(8))) short bh8;   // 8 bf16 = 4 VGPR
typedef __attribute__((ext_vector_type(4))) float f4;    // MFMA acc

#define LOG2E 1.44269504088896f
#define QSCALE 0.18033688f   // 0.125 * log2(e), folded into Q at GEMM1 epilogue

__device__ inline u16 f2bf(float f) {
  union { float f; uint32_t u; } c; c.f = f;
  uint32_t u = c.u;
  return (u16)((u + 0x7fffu + ((u >> 16) & 1u)) >> 16);  // RNE
}

__device__ inline float fast_exp2(float x) {
#if __has_builtin(__builtin_amdgcn_exp2f)
  return __builtin_amdgcn_exp2f(x);
#else
  return exp2f(x);
#endif
}

// pack hi16 of two u32s into one u32: dst = (a>>16) | (b & 0xFFFF0000).
// v_perm_b32 byte-extract, sel 0x07060302 — BIT-IDENTICAL to the shift-or chain.
__device__ inline uint32_t pack_hi16(uint32_t a, uint32_t b) {
#if __has_builtin(__builtin_amdgcn_perm)
  return __builtin_amdgcn_perm(b, a, 0x07060302u);
#else
  return (a >> 16) | (b & 0xFFFF0000u);
#endif
}

#if __has_builtin(__builtin_amdgcn_global_load_lds)
#define GLD16(gp, lp) __builtin_amdgcn_global_load_lds( \
    (const __attribute__((address_space(1))) void*)(gp), \
    (__attribute__((address_space(3))) void*)(lp), 16, 0, 0)
#else
#define GLD16(gp, lp) do { *(bh8*)(lp) = *(const bh8*)(gp); } while (0)
#endif

#if __has_builtin(__builtin_amdgcn_s_setprio)
#define SETPRIO(n) __builtin_amdgcn_s_setprio(n)
#else
#define SETPRIO(n) do {} while (0)
#endif

// ---------------- merged prep: x cvt + both weight transposes ----------------------
// Blocks [0,8192): x f32->bf16. [8192,11264): w_qkv transpose. [11264,12288): w_out.

__device__ inline void transpose_tile_256(const float* __restrict__ src,
                                          u16* __restrict__ dst, int K, int N,
                                          int k0, int n0, float (*tile)[33]) {
  int tx = threadIdx.x & 31, ty0 = threadIdx.x >> 5;
#pragma unroll
  for (int s = 0; s < 4; ++s) {
    int ty = ty0 + s * 8;
    tile[ty][tx] = src[(size_t)(k0 + ty) * N + n0 + tx];
  }
  __syncthreads();
#pragma unroll
  for (int s = 0; s < 4; ++s) {
    int ty = ty0 + s * 8;
    dst[(size_t)(n0 + ty) * K + k0 + tx] = f2bf(tile[tx][ty]);
  }
}

__global__ __launch_bounds__(256) void prep(const float* __restrict__ x,
                                            u16* __restrict__ xb,
                                            const float* __restrict__ w_qkv,
                                            u16* __restrict__ wqt,
                                            const float* __restrict__ w_out,
                                            u16* __restrict__ wot) {
  __shared__ float tile[32][33];
  const int bid = blockIdx.x;
  if (bid < 8192) {
    int i = bid * 256 + threadIdx.x;
    float4 v = ((const float4*)x)[i];
    ushort4 o;
    o.x = f2bf(v.x); o.y = f2bf(v.y); o.z = f2bf(v.z); o.w = f2bf(v.w);
    ((ushort4*)xb)[i] = o;
  } else if (bid < 8192 + 3072) {
    int t = bid - 8192;                       // w_qkv: N=3072 (96 n-tiles), K=1024
    transpose_tile_256(w_qkv, wqt, 1024, 3072, (t / 96) * 32, (t % 96) * 32, tile);
  } else {
    int t = bid - 11264;                      // w_out: N=1024 (32 n-tiles), K=1024
    transpose_tile_256(w_out, wot, 1024, 1024, (t / 32) * 32, (t % 32) * 32, tile);
  }
}

// ---------------- GEMM mainloop (C = A @ Bt^T), 128x128 tile, BK=64 ----------------
__device__ inline void gemm_mainloop(const u16* __restrict__ A, const u16* __restrict__ Bt,
                                     int K, int m0, int n0,
                                     u16* As, u16* Bs, f4 acc[4][4]) {
  const int tid  = threadIdx.x;
  const int lane = tid & 63;
  const int quad = lane >> 4;
  const int ml   = lane & 15;
  const int wave = tid >> 6;
  const int wm   = (wave >> 1) * 64;
  const int wn   = (wave & 1) * 64;

#pragma unroll 1
  for (int k0 = 0; k0 < K; k0 += 64) {
#pragma unroll
    for (int r = 0; r < 4; ++r) {
      int chunk = r * 256 + tid;
      int row = chunk >> 3, cc = chunk & 7;
      int cg = cc ^ (row & 7);
      GLD16(A + (size_t)(m0 + row) * K + k0 + cg * 8, As + chunk * 8);
    }
#pragma unroll
    for (int r = 0; r < 4; ++r) {
      int chunk = r * 256 + tid;
      int row = chunk >> 3, cc = chunk & 7;
      int cg = cc ^ (row & 7);
      GLD16(Bt + (size_t)(n0 + row) * K + k0 + cg * 8, Bs + chunk * 8);
    }
    __syncthreads();
#pragma unroll
    for (int ks = 0; ks < 2; ++ks) {
      bh8 af[4], bfr[4];
      int cs = (ks * 4 + quad) ^ (ml & 7);
#pragma unroll
      for (int i = 0; i < 4; ++i) {
        int row = wm + i * 16 + ml;
        af[i] = *(const bh8*)(As + (row * 8 + cs) * 8);
      }
#pragma unroll
      for (int j = 0; j < 4; ++j) {
        int row = wn + j * 16 + ml;
        bfr[j] = *(const bh8*)(Bs + (row * 8 + cs) * 8);
      }
#pragma unroll
      for (int i = 0; i < 4; ++i)
#pragma unroll
        for (int j = 0; j < 4; ++j)
          acc[i][j] = __builtin_amdgcn_mfma_f32_16x16x32_bf16(af[i], bfr[j], acc[i][j], 0, 0, 0);
    }
    __syncthreads();
  }
}

// ---------------- GEMM1: qkv = x @ w_qkv + b ----------------
// q scaled by QSCALE; q,k stored [bh][l][d]; V stored DIRECTLY TRANSPOSED [bh][d][l].
// XCD-locality swizzle: xcd = wgid&7, contiguous m-band per XCD.
__global__ __launch_bounds__(256) void gemm_qkv(const u16* __restrict__ xb,
                                                const u16* __restrict__ wqt,
                                                const float* __restrict__ bqkv,
                                                u16* __restrict__ q, u16* __restrict__ k,
                                                u16* __restrict__ v) {
  __shared__ __align__(16) u16 smem[2 * 128 * 64];
  const f4 fzero = {0.f, 0.f, 0.f, 0.f};
  f4 acc[4][4];
#pragma unroll
  for (int i = 0; i < 4; ++i)
#pragma unroll
    for (int j = 0; j < 4; ++j) acc[i][j] = fzero;

  const int wgid = blockIdx.x;                 // 0..1535
  const int xcd = wgid & 7, loc = wgid >> 3;   // loc in [0,192)
  const int mt = xcd * 8 + loc / 24;           // m-tile 0..63
  const int nt = loc % 24;                     // n-tile 0..23
  int m0 = mt * 128, n0 = nt * 128;
  gemm_mainloop(xb, wqt, 1024, m0, n0, smem, smem + 128 * 64, acc);

  const int lane = threadIdx.x & 63, wave = threadIdx.x >> 6;
  const int quad = lane >> 4, ml = lane & 15;
  const int wm = (wave >> 1) * 64, wn = (wave & 1) * 64;
  if (n0 < 2048) {
    u16* dst = (n0 < 1024) ? q : k;
    float scale = (n0 < 1024) ? QSCALE : 1.0f;
#pragma unroll
    for (int j = 0; j < 4; ++j) {
      int nn = n0 + wn + j * 16 + ml;
      int h = (nn >> 6) & 15, d = nn & 63;
      float bias = bqkv[nn];
#pragma unroll
      for (int i = 0; i < 4; ++i) {
#pragma unroll
        for (int r = 0; r < 4; ++r) {
          int tok = m0 + wm + i * 16 + quad * 4 + r;
          int b = tok >> 11, l = tok & 2047;
          int bh = b * 16 + h;
          dst[((size_t)bh * 2048 + l) * 64 + d] = f2bf((acc[i][j][r] + bias) * scale);
        }
      }
    }
  } else {
    // V path: store transposed [bh][d][2048], 8B vector stores
#pragma unroll
    for (int j = 0; j < 4; ++j) {
      int nn = n0 + wn + j * 16 + ml;
      int h = (nn >> 6) & 15, d = nn & 63;
      float bias = bqkv[nn];
#pragma unroll
      for (int i = 0; i < 4; ++i) {
        int tok = m0 + wm + i * 16 + quad * 4;   // r=0 base; +r stays in-batch
        int b = tok >> 11, l = tok & 2047;
        int bh = b * 16 + h;
        ushort4 w;
        w.x = f2bf(acc[i][j][0] + bias);
        w.y = f2bf(acc[i][j][1] + bias);
        w.z = f2bf(acc[i][j][2] + bias);
        w.w = f2bf(acc[i][j][3] + bias);
        *(ushort4*)&v[((size_t)bh * 64 + d) * 2048 + l] = w;
      }
    }
  }
}

// ---------------- GEMM2: out = o @ w_out + b_out (fp32 out), 64x128 tile -----------
// XCD-locality swizzle.
__global__ __launch_bounds__(256) void gemm_out64(const u16* __restrict__ ob,
                                                  const u16* __restrict__ wot,
                                                  const float* __restrict__ bout,
                                                  float* __restrict__ out) {
  __shared__ __align__(16) u16 As[64 * 64];
  __shared__ __align__(16) u16 Bs[128 * 64];
  const int tid  = threadIdx.x;
  const int lane = tid & 63;
  const int quad = lane >> 4;
  const int ml   = lane & 15;
  const int wave = tid >> 6;
  const int wm   = (wave >> 1) * 32;   // 2 wave-rows x 32
  const int wn   = (wave & 1) * 64;    // 2 wave-cols x 64
  const int wgid = blockIdx.x;                  // 0..1023
  const int xcd = wgid & 7, loc = wgid >> 3;    // loc in [0,128)
  const int mt = xcd * 16 + loc / 8;            // m-tile 0..127
  const int nt = loc % 8;                       // n-tile 0..7
  const int m0 = mt * 64, n0 = nt * 128;

  const f4 fzero = {0.f, 0.f, 0.f, 0.f};
  f4 acc[2][4];
#pragma unroll
  for (int i = 0; i < 2; ++i)
#pragma unroll
    for (int j = 0; j < 4; ++j) acc[i][j] = fzero;

  const int srow = tid >> 3, scc = tid & 7;
  const int scg = scc ^ (srow & 7);

#pragma unroll 1
  for (int k0 = 0; k0 < 1024; k0 += 64) {
#pragma unroll
    for (int r = 0; r < 2; ++r) {
      int row = r * 32 + srow;   // [0,64)
      GLD16(ob + (size_t)(m0 + row) * 1024 + k0 + scg * 8, As + (row * 8 + scc) * 8);
    }
#pragma unroll
    for (int r = 0; r < 4; ++r) {
      int row = r * 32 + srow;   // [0,128)
      GLD16(wot + (size_t)(n0 + row) * 1024 + k0 + scg * 8, Bs + (row * 8 + scc) * 8);
    }
    __syncthreads();
#pragma unroll
    for (int ks = 0; ks < 2; ++ks) {
      int cs = (ks * 4 + quad) ^ (ml & 7);
      bh8 af[2], bfr[4];
#pragma unroll
      for (int i = 0; i < 2; ++i)
        af[i] = *(const bh8*)(As + ((wm + i * 16 + ml) * 8 + cs) * 8);
#pragma unroll
      for (int j = 0; j < 4; ++j)
        bfr[j] = *(const bh8*)(Bs + ((wn + j * 16 + ml) * 8 + cs) * 8);
#pragma unroll
      for (int i = 0; i < 2; ++i)
#pragma unroll
        for (int j = 0; j < 4; ++j)
          acc[i][j] = __builtin_amdgcn_mfma_f32_16x16x32_bf16(af[i], bfr[j], acc[i][j], 0, 0, 0);
    }
    __syncthreads();
  }

#pragma unroll
  for (int j = 0; j < 4; ++j) {
    int nn = n0 + wn + j * 16 + ml;
    float bias = bout[nn];
#pragma unroll
    for (int i = 0; i < 2; ++i)
#pragma unroll
      for (int r = 0; r < 4; ++r) {
        int tok = m0 + wm + i * 16 + quad * 4 + r;
        out[(size_t)tok * 1024 + nn] = acc[i][j][r] + bias;
      }
  }
}

// ---------------- flash attention v16: 8-wave blocks share one K/V staging ---------
// Round-15 postmortem: v15 attn = 91.5us with no pipe saturated; the remaining
// structural waste is 4 independent blocks/CU EACH staging their own copy of the
// same K/V tiles (4x redundant LDS-write + L2->LDS traffic). v16: 512-thread
// blocks (8 waves) share ONE staging pass — per-wave algebra BYTE-IDENTICAL, only
// re-parameterized: wave in [0,8), qw = y*256 + wave*32, grid (64,8); staging's
// srow = tid>>3 now spans all 64 rows (exactly 1 K + 1 V GLD16 per thread/tile).
// Occupancy unchanged (2 blocks x 8 waves = 16 waves/CU); VGPR 64 (cap 128 at
// __launch_bounds__(512,4)); LDS 48KB x 2 = 96KB. Staged bytes per q-row HALVE;
// predicted FETCH 24.6 -> ~16-18MB. Risk: coarser barrier (8-wave sync, 2-block
// overlap) — if attn > 92us, revert.
// Conflict history: v10 4.19M -> v11 2.10M -> v13 0 (bit1-separated pf pair).
// Numerics: half-up pack (v_perm byte-extract, bit-identical) + ones-MFMA
// denominator. v_cvt_pk_bf16_f32 BANNED (failed twice).
__global__ __launch_bounds__(512, 4) void attn(const u16* __restrict__ q,
                                               const u16* __restrict__ k,
                                               const u16* __restrict__ vt,
                                               u16* __restrict__ o) {
  __shared__ __align__(16) u16 Ks[2][64 * 64];    // row=key, 8 chunks, XOR swizzle
  __shared__ __align__(16) u16 Vs[2][64 * 64];    // row=d,   cols=key, XOR swizzle
  __shared__ __align__(16) u16 Pq[8][16 * 64];    // per-wave P, per-ml 128B regions
  const int bh = blockIdx.x;
  const int b = bh >> 4, h = bh & 15;
  const int tid = threadIdx.x;
  const int wave = tid >> 6, lane = tid & 63;
  const int quad = lane >> 4, ml = lane & 15;
  const int qw = blockIdx.y * 256 + wave * 32;
  const u16* qp = q + (size_t)bh * 2048 * 64;
  const u16* kp = k + (size_t)bh * 2048 * 64;
  const u16* vp = vt + (size_t)bh * 64 * 2048;
  const f4 fzero = {0.f, 0.f, 0.f, 0.f};

  const int mlx = ml & 7;    // XOR bits for Ks/Vs 16B-chunk swizzle

  // ones A-fragment for the li row-sum MFMA (bf16 1.0 in every element)
  bh8 ones;
#pragma unroll
  for (int t = 0; t < 8; ++t) ones[t] = (short)0x3F80;

  // Q fragments: B-operand, rows qw+g*16+ml, 16B contiguous
  bh8 qf[2][2];
#pragma unroll
  for (int g = 0; g < 2; ++g)
#pragma unroll
    for (int ks = 0; ks < 2; ++ks)
      qf[g][ks] = *(const bh8*)&qp[(size_t)(qw + g * 16 + ml) * 64 + ks * 32 + quad * 8];

  f4 oacc[2][4], liacc[2];
#pragma unroll
  for (int g = 0; g < 2; ++g) {
#pragma unroll
    for (int j = 0; j < 4; ++j) oacc[g][j] = fzero;
    liacc[g] = fzero;
  }

  // staging: 512 threads cover 64 rows x 8 chunks, 1 GLD16 each for K and V
  const int srow = tid >> 3, scc = tid & 7;       // srow in [0,64)
  const int scg = scc ^ (srow & 7);
  u16* pq = &Pq[wave][ml * 64];   // this lane's 128B region: 16 slots x 8B

  // prologue: stage K+V tile 0 into buffer 0
  GLD16(kp + (size_t)srow * 64 + scg * 8, &Ks[0][(srow * 8 + scc) * 8]);
  GLD16(vp + (size_t)srow * 2048 + scg * 8, &Vs[0][(srow * 8 + scc) * 8]);
  __syncthreads();

  int cur = 0;
#pragma unroll 1
  for (int t = 0; t < 32; ++t) {
    // stage next K+V tile into the other buffer (in flight until end-of-tile drain)
    if (t < 31) {
      int ktn = (t + 1) * 64;
      GLD16(kp + (size_t)(ktn + srow) * 64 + scg * 8, &Ks[cur ^ 1][(srow * 8 + scc) * 8]);
      GLD16(vp + (size_t)srow * 2048 + ktn + scg * 8, &Vs[cur ^ 1][(srow * 8 + scc) * 8]);
    }

    // S^T = K @ Q^T from LDS: s[g][j][r] = S[q=qw+g*16+ml][kt + 16j + 4quad + r]
    f4 s[2][4];
#pragma unroll
    for (int g = 0; g < 2; ++g)
#pragma unroll
      for (int j = 0; j < 4; ++j) s[g][j] = fzero;
#pragma unroll
    for (int ks = 0; ks < 2; ++ks) {
      int cs = (ks * 4 + quad) ^ mlx;
      bh8 kf[4];
#pragma unroll
      for (int j = 0; j < 4; ++j)
        kf[j] = *(const bh8*)(&Ks[cur][((j * 16 + ml) * 8 + cs) * 8]);
      SETPRIO(1);
#pragma unroll
      for (int j = 0; j < 4; ++j) {
        s[0][j] = __builtin_amdgcn_mfma_f32_16x16x32_bf16(kf[j], qf[0][ks], s[0][j], 0, 0, 0);
        s[1][j] = __builtin_amdgcn_mfma_f32_16x16x32_bf16(kf[j], qf[1][ks], s[1][j], 0, 0, 0);
      }
      SETPRIO(0);
    }

    // two ks-phases: softmax keys [32ks,32ks+32) -> write -> pf read -> PV + li.
    // Pq slots reused across phases (same-wave DS in-order => WAR safe).
#pragma unroll
    for (int ks = 0; ks < 2; ++ks) {
      // p = exp2(s) -> bf16 half-up; pack via v_perm byte-extract (bit-identical)
#pragma unroll
      for (int g = 0; g < 2; ++g) {
#pragma unroll
        for (int jl = 0; jl < 2; ++jl) {
          int j = ks * 2 + jl;
          uint32_t w[4];
#pragma unroll
          for (int r = 0; r < 4; ++r) {
            union { float f; uint32_t u; } c;
            c.f = fast_exp2(s[g][j][r]);
            w[r] = c.u + 0x8000u;
          }
          uint2 pk;
          pk.x = pack_hi16(w[0], w[1]);
          pk.y = pack_hi16(w[2], w[3]);
          // slot: bit0 <- quad&1, bit1 <- quad>>1 (pair-distinction lives in bit1)
          int sl = (g * 8 + jl * 4 + 2 * (quad & 1) + (quad >> 1)) ^ ml;
          *(uint2*)(pq + (sl << 2)) = pk;
        }
      }

      // O^T += V^T @ P^T ; li += 1 @ P^T  (vf from LDS, reused for both groups;
      // pf via two b64 reads 16B apart -> unmergeable, conflict-free)
      int cs = (ks * 4 + quad) ^ mlx;
      bh8 vf[4];
#pragma unroll
      for (int j = 0; j < 4; ++j)
        vf[j] = *(const bh8*)(&Vs[cur][((j * 16 + ml) * 8 + cs) * 8]);
#pragma unroll
      for (int g = 0; g < 2; ++g) {
        int slo = (g * 8 + 4 * (quad >> 1) + (quad & 1)) ^ ml;
        int shi = slo ^ 2;
        uint2 lo = *(const uint2*)(pq + (slo << 2));
        uint2 hi = *(const uint2*)(pq + (shi << 2));
        union { uint32_t u[4]; bh8 v; } pf;
        pf.u[0] = lo.x; pf.u[1] = lo.y; pf.u[2] = hi.x; pf.u[3] = hi.y;
        SETPRIO(1);
#pragma unroll
        for (int j = 0; j < 4; ++j)
          oacc[g][j] = __builtin_amdgcn_mfma_f32_16x16x32_bf16(vf[j], pf.v, oacc[g][j], 0, 0, 0);
        liacc[g] = __builtin_amdgcn_mfma_f32_16x16x32_bf16(ones, pf.v, liacc[g], 0, 0, 0);
        SETPRIO(0);
      }
    }
    __syncthreads();   // drains K/V stage (vmcnt) + all LDS reads of buf[cur]
    cur ^= 1;
  }

  // li[g] came through the same bf16 P as the numerator; every acc row holds the
  // full row-sum for q=qw+g*16+ml (ones x P^T), so no cross-lane reduction needed.
#pragma unroll
  for (int g = 0; g < 2; ++g) {
    float inv = 1.0f / liacc[g][0];
    // store o as (b, l, h, d) bf16; lane holds q=qw+g*16+ml, d=16j+4quad+r
    size_t obase = (((size_t)b * 2048 + qw + g * 16 + ml) * 16 + h) * 64;
#pragma unroll
    for (int j = 0; j < 4; ++j) {
      ushort4 w;
      w.x = f2bf(oacc[g][j][0] * inv);
      w.y = f2bf(oacc[g][j][1] * inv);
      w.z = f2bf(oacc[g][j][2] * inv);
      w.w = f2bf(oacc[g][j][3] * inv);
      *(ushort4*)(o + obase + j * 16 + quad * 4) = w;
    }
  }
}

// ---------------- launch ----------------
// prep = merged cvt + weight transposes. gemm_qkv writes vt DIRECTLY into vb
// (transposed); attn (512-thread 8-wave blocks, grid (64,8)) writes o into xb;
// gemm_out64 reads xb. GEMM grids 1-D with in-kernel XCD decomposition.

extern "C" void kernel_launch(void* const* d_in, const int* in_sizes, int n_in,
                              void* d_out, int out_size, void* d_ws, size_t ws_size,
                              hipStream_t stream) {
  const float* x     = (const float*)d_in[0];
  const float* w_qkv = (const float*)d_in[1];
  const float* b_qkv = (const float*)d_in[2];
  const float* w_out = (const float*)d_in[3];
  const float* b_out = (const float*)d_in[4];
  float* out = (float*)d_out;

  u16* ws  = (u16*)d_ws;
  u16* xb  = ws;                                  // 8192*1024 (o reuses after gemm_qkv)
  u16* wqt = xb + (size_t)8192 * 1024;            // 3072*1024
  u16* wot = wqt + (size_t)3072 * 1024;           // 1024*1024
  u16* qb  = wot + (size_t)1024 * 1024;           // 64*2048*64
  u16* kb  = qb + (size_t)64 * 2048 * 64;
  u16* vb  = kb + (size_t)64 * 2048 * 64;         // vt [bh][d][l] (written directly)
  u16* ob  = xb;   // xb dead after gemm_qkv

  prep<<<12288, 256, 0, stream>>>(x, xb, w_qkv, wqt, w_out, wot);
  gemm_qkv<<<1536, 256, 0, stream>>>(xb, wqt, b_qkv, qb, kb, vb);
  attn<<<dim3(64, 8), 512, 0, stream>>>(qb, kb, vb, ob);
  gemm_out64<<<1024, 256, 0, stream>>>(ob, wot, b_out, out);
}

// Round 17
// 262.384 us; speedup vs baseline: 1.0411x; 1.0045x over previous
//
#include <hip/hip_runtime.h>
#include <stdint.h>

typedef unsigned short u16;
typedef __attribute__((ext_vector_type(8))) short bh8;   // 8 bf16 = 4 VGPR
typedef __attribute__((ext_vector_type(4))) float f4;    // MFMA acc

#define LOG2E 1.44269504088896f
#define QSCALE 0.18033688f   // 0.125 * log2(e), folded into Q at GEMM1 epilogue

__device__ inline u16 f2bf(float f) {
  union { float f; uint32_t u; } c; c.f = f;
  uint32_t u = c.u;
  return (u16)((u + 0x7fffu + ((u >> 16) & 1u)) >> 16);  // RNE
}

__device__ inline float fast_exp2(float x) {
#if __has_builtin(__builtin_amdgcn_exp2f)
  return __builtin_amdgcn_exp2f(x);
#else
  return exp2f(x);
#endif
}

// pack hi16 of two u32s into one u32: dst = (a>>16) | (b & 0xFFFF0000).
// v_perm_b32 byte-extract, sel 0x07060302 — BIT-IDENTICAL to the shift-or chain.
__device__ inline uint32_t pack_hi16(uint32_t a, uint32_t b) {
#if __has_builtin(__builtin_amdgcn_perm)
  return __builtin_amdgcn_perm(b, a, 0x07060302u);
#else
  return (a >> 16) | (b & 0xFFFF0000u);
#endif
}

#if __has_builtin(__builtin_amdgcn_global_load_lds)
#define GLD16(gp, lp) __builtin_amdgcn_global_load_lds( \
    (const __attribute__((address_space(1))) void*)(gp), \
    (__attribute__((address_space(3))) void*)(lp), 16, 0, 0)
#else
#define GLD16(gp, lp) do { *(bh8*)(lp) = *(const bh8*)(gp); } while (0)
#endif

#if __has_builtin(__builtin_amdgcn_s_setprio)
#define SETPRIO(n) __builtin_amdgcn_s_setprio(n)
#else
#define SETPRIO(n) do {} while (0)
#endif

// ---------------- merged prep: x cvt + both weight transposes ----------------------
// Blocks [0,8192): x f32->bf16. [8192,11264): w_qkv transpose. [11264,12288): w_out.

__device__ inline void transpose_tile_256(const float* __restrict__ src,
                                          u16* __restrict__ dst, int K, int N,
                                          int k0, int n0, float (*tile)[33]) {
  int tx = threadIdx.x & 31, ty0 = threadIdx.x >> 5;
#pragma unroll
  for (int s = 0; s < 4; ++s) {
    int ty = ty0 + s * 8;
    tile[ty][tx] = src[(size_t)(k0 + ty) * N + n0 + tx];
  }
  __syncthreads();
#pragma unroll
  for (int s = 0; s < 4; ++s) {
    int ty = ty0 + s * 8;
    dst[(size_t)(n0 + ty) * K + k0 + tx] = f2bf(tile[tx][ty]);
  }
}

__global__ __launch_bounds__(256) void prep(const float* __restrict__ x,
                                            u16* __restrict__ xb,
                                            const float* __restrict__ w_qkv,
                                            u16* __restrict__ wqt,
                                            const float* __restrict__ w_out,
                                            u16* __restrict__ wot) {
  __shared__ float tile[32][33];
  const int bid = blockIdx.x;
  if (bid < 8192) {
    int i = bid * 256 + threadIdx.x;
    float4 v = ((const float4*)x)[i];
    ushort4 o;
    o.x = f2bf(v.x); o.y = f2bf(v.y); o.z = f2bf(v.z); o.w = f2bf(v.w);
    ((ushort4*)xb)[i] = o;
  } else if (bid < 8192 + 3072) {
    int t = bid - 8192;                       // w_qkv: N=3072 (96 n-tiles), K=1024
    transpose_tile_256(w_qkv, wqt, 1024, 3072, (t / 96) * 32, (t % 96) * 32, tile);
  } else {
    int t = bid - 11264;                      // w_out: N=1024 (32 n-tiles), K=1024
    transpose_tile_256(w_out, wot, 1024, 1024, (t / 32) * 32, (t % 32) * 32, tile);
  }
}

// ---------------- GEMM mainloop (C = A @ Bt^T), 128x128 tile, BK=64 ----------------
__device__ inline void gemm_mainloop(const u16* __restrict__ A, const u16* __restrict__ Bt,
                                     int K, int m0, int n0,
                                     u16* As, u16* Bs, f4 acc[4][4]) {
  const int tid  = threadIdx.x;
  const int lane = tid & 63;
  const int quad = lane >> 4;
  const int ml   = lane & 15;
  const int wave = tid >> 6;
  const int wm   = (wave >> 1) * 64;
  const int wn   = (wave & 1) * 64;

#pragma unroll 1
  for (int k0 = 0; k0 < K; k0 += 64) {
#pragma unroll
    for (int r = 0; r < 4; ++r) {
      int chunk = r * 256 + tid;
      int row = chunk >> 3, cc = chunk & 7;
      int cg = cc ^ (row & 7);
      GLD16(A + (size_t)(m0 + row) * K + k0 + cg * 8, As + chunk * 8);
    }
#pragma unroll
    for (int r = 0; r < 4; ++r) {
      int chunk = r * 256 + tid;
      int row = chunk >> 3, cc = chunk & 7;
      int cg = cc ^ (row & 7);
      GLD16(Bt + (size_t)(n0 + row) * K + k0 + cg * 8, Bs + chunk * 8);
    }
    __syncthreads();
#pragma unroll
    for (int ks = 0; ks < 2; ++ks) {
      bh8 af[4], bfr[4];
      int cs = (ks * 4 + quad) ^ (ml & 7);
#pragma unroll
      for (int i = 0; i < 4; ++i) {
        int row = wm + i * 16 + ml;
        af[i] = *(const bh8*)(As + (row * 8 + cs) * 8);
      }
#pragma unroll
      for (int j = 0; j < 4; ++j) {
        int row = wn + j * 16 + ml;
        bfr[j] = *(const bh8*)(Bs + (row * 8 + cs) * 8);
      }
#pragma unroll
      for (int i = 0; i < 4; ++i)
#pragma unroll
        for (int j = 0; j < 4; ++j)
          acc[i][j] = __builtin_amdgcn_mfma_f32_16x16x32_bf16(af[i], bfr[j], acc[i][j], 0, 0, 0);
    }
    __syncthreads();
  }
}

// ---------------- GEMM1: qkv = x @ w_qkv + b ----------------
// q scaled by QSCALE; q,k stored [bh][l][d]; V stored DIRECTLY TRANSPOSED [bh][d][l].
// XCD-locality swizzle: xcd = wgid&7, contiguous m-band per XCD.
// Round-17: __launch_bounds__(256,4) — guarantee 4 blocks/CU (16 waves). Live state
// ~100 VGPR < 128 cap, so no spill expected (WRITE_SIZE is the canary).
__global__ __launch_bounds__(256, 4) void gemm_qkv(const u16* __restrict__ xb,
                                                   const u16* __restrict__ wqt,
                                                   const float* __restrict__ bqkv,
                                                   u16* __restrict__ q, u16* __restrict__ k,
                                                   u16* __restrict__ v) {
  __shared__ __align__(16) u16 smem[2 * 128 * 64];
  const f4 fzero = {0.f, 0.f, 0.f, 0.f};
  f4 acc[4][4];
#pragma unroll
  for (int i = 0; i < 4; ++i)
#pragma unroll
    for (int j = 0; j < 4; ++j) acc[i][j] = fzero;

  const int wgid = blockIdx.x;                 // 0..1535
  const int xcd = wgid & 7, loc = wgid >> 3;   // loc in [0,192)
  const int mt = xcd * 8 + loc / 24;           // m-tile 0..63
  const int nt = loc % 24;                     // n-tile 0..23
  int m0 = mt * 128, n0 = nt * 128;
  gemm_mainloop(xb, wqt, 1024, m0, n0, smem, smem + 128 * 64, acc);

  const int lane = threadIdx.x & 63, wave = threadIdx.x >> 6;
  const int quad = lane >> 4, ml = lane & 15;
  const int wm = (wave >> 1) * 64, wn = (wave & 1) * 64;
  if (n0 < 2048) {
    u16* dst = (n0 < 1024) ? q : k;
    float scale = (n0 < 1024) ? QSCALE : 1.0f;
#pragma unroll
    for (int j = 0; j < 4; ++j) {
      int nn = n0 + wn + j * 16 + ml;
      int h = (nn >> 6) & 15, d = nn & 63;
      float bias = bqkv[nn];
#pragma unroll
      for (int i = 0; i < 4; ++i) {
#pragma unroll
        for (int r = 0; r < 4; ++r) {
          int tok = m0 + wm + i * 16 + quad * 4 + r;
          int b = tok >> 11, l = tok & 2047;
          int bh = b * 16 + h;
          dst[((size_t)bh * 2048 + l) * 64 + d] = f2bf((acc[i][j][r] + bias) * scale);
        }
      }
    }
  } else {
    // V path: store transposed [bh][d][2048], 8B vector stores
#pragma unroll
    for (int j = 0; j < 4; ++j) {
      int nn = n0 + wn + j * 16 + ml;
      int h = (nn >> 6) & 15, d = nn & 63;
      float bias = bqkv[nn];
#pragma unroll
      for (int i = 0; i < 4; ++i) {
        int tok = m0 + wm + i * 16 + quad * 4;   // r=0 base; +r stays in-batch
        int b = tok >> 11, l = tok & 2047;
        int bh = b * 16 + h;
        ushort4 w;
        w.x = f2bf(acc[i][j][0] + bias);
        w.y = f2bf(acc[i][j][1] + bias);
        w.z = f2bf(acc[i][j][2] + bias);
        w.w = f2bf(acc[i][j][3] + bias);
        *(ushort4*)&v[((size_t)bh * 64 + d) * 2048 + l] = w;
      }
    }
  }
}

// ---------------- GEMM2: out = o @ w_out + b_out (fp32 out), 64x128 tile -----------
// XCD-locality swizzle. Round-17: __launch_bounds__(256,4) occupancy guarantee.
__global__ __launch_bounds__(256, 4) void gemm_out64(const u16* __restrict__ ob,
                                                     const u16* __restrict__ wot,
                                                     const float* __restrict__ bout,
                                                     float* __restrict__ out) {
  __shared__ __align__(16) u16 As[64 * 64];
  __shared__ __align__(16) u16 Bs[128 * 64];
  const int tid  = threadIdx.x;
  const int lane = tid & 63;
  const int quad = lane >> 4;
  const int ml   = lane & 15;
  const int wave = tid >> 6;
  const int wm   = (wave >> 1) * 32;   // 2 wave-rows x 32
  const int wn   = (wave & 1) * 64;    // 2 wave-cols x 64
  const int wgid = blockIdx.x;                  // 0..1023
  const int xcd = wgid & 7, loc = wgid >> 3;    // loc in [0,128)
  const int mt = xcd * 16 + loc / 8;            // m-tile 0..127
  const int nt = loc % 8;                       // n-tile 0..7
  const int m0 = mt * 64, n0 = nt * 128;

  const f4 fzero = {0.f, 0.f, 0.f, 0.f};
  f4 acc[2][4];
#pragma unroll
  for (int i = 0; i < 2; ++i)
#pragma unroll
    for (int j = 0; j < 4; ++j) acc[i][j] = fzero;

  const int srow = tid >> 3, scc = tid & 7;
  const int scg = scc ^ (srow & 7);

#pragma unroll 1
  for (int k0 = 0; k0 < 1024; k0 += 64) {
#pragma unroll
    for (int r = 0; r < 2; ++r) {
      int row = r * 32 + srow;   // [0,64)
      GLD16(ob + (size_t)(m0 + row) * 1024 + k0 + scg * 8, As + (row * 8 + scc) * 8);
    }
#pragma unroll
    for (int r = 0; r < 4; ++r) {
      int row = r * 32 + srow;   // [0,128)
      GLD16(wot + (size_t)(n0 + row) * 1024 + k0 + scg * 8, Bs + (row * 8 + scc) * 8);
    }
    __syncthreads();
#pragma unroll
    for (int ks = 0; ks < 2; ++ks) {
      int cs = (ks * 4 + quad) ^ (ml & 7);
      bh8 af[2], bfr[4];
#pragma unroll
      for (int i = 0; i < 2; ++i)
        af[i] = *(const bh8*)(As + ((wm + i * 16 + ml) * 8 + cs) * 8);
#pragma unroll
      for (int j = 0; j < 4; ++j)
        bfr[j] = *(const bh8*)(Bs + ((wn + j * 16 + ml) * 8 + cs) * 8);
#pragma unroll
      for (int i = 0; i < 2; ++i)
#pragma unroll
        for (int j = 0; j < 4; ++j)
          acc[i][j] = __builtin_amdgcn_mfma_f32_16x16x32_bf16(af[i], bfr[j], acc[i][j], 0, 0, 0);
    }
    __syncthreads();
  }

#pragma unroll
  for (int j = 0; j < 4; ++j) {
    int nn = n0 + wn + j * 16 + ml;
    float bias = bout[nn];
#pragma unroll
    for (int i = 0; i < 2; ++i)
#pragma unroll
      for (int r = 0; r < 4; ++r) {
        int tok = m0 + wm + i * 16 + quad * 4 + r;
        out[(size_t)tok * 1024 + nn] = acc[i][j][r] + bias;
      }
  }
}

// ---------------- flash attention v16 (frozen: proven 87.6us, 0 conflicts) ---------
// 512-thread 8-wave blocks share ONE K/V staging pass (2 blocks/CU, 16 waves).
// Conflict history: v10 4.19M -> v11 2.10M (compiler b128-merge of adjacent read
// pair drops ml bit0) -> v13 0 (bit1-separated pair, unmergeable). Numerics:
// half-up pack (v_perm byte-extract, bit-identical) + ones-MFMA denominator
// (same bf16 P for num and den -> rounding bias cancels). v_cvt_pk_bf16_f32
// BANNED (failed twice: packing semantics differ from assumption).
__global__ __launch_bounds__(512, 4) void attn(const u16* __restrict__ q,
                                               const u16* __restrict__ k,
                                               const u16* __restrict__ vt,
                                               u16* __restrict__ o) {
  __shared__ __align__(16) u16 Ks[2][64 * 64];    // row=key, 8 chunks, XOR swizzle
  __shared__ __align__(16) u16 Vs[2][64 * 64];    // row=d,   cols=key, XOR swizzle
  __shared__ __align__(16) u16 Pq[8][16 * 64];    // per-wave P, per-ml 128B regions
  const int bh = blockIdx.x;
  const int b = bh >> 4, h = bh & 15;
  const int tid = threadIdx.x;
  const int wave = tid >> 6, lane = tid & 63;
  const int quad = lane >> 4, ml = lane & 15;
  const int qw = blockIdx.y * 256 + wave * 32;
  const u16* qp = q + (size_t)bh * 2048 * 64;
  const u16* kp = k + (size_t)bh * 2048 * 64;
  const u16* vp = vt + (size_t)bh * 64 * 2048;
  const f4 fzero = {0.f, 0.f, 0.f, 0.f};

  const int mlx = ml & 7;    // XOR bits for Ks/Vs 16B-chunk swizzle

  // ones A-fragment for the li row-sum MFMA (bf16 1.0 in every element)
  bh8 ones;
#pragma unroll
  for (int t = 0; t < 8; ++t) ones[t] = (short)0x3F80;

  // Q fragments: B-operand, rows qw+g*16+ml, 16B contiguous
  bh8 qf[2][2];
#pragma unroll
  for (int g = 0; g < 2; ++g)
#pragma unroll
    for (int ks = 0; ks < 2; ++ks)
      qf[g][ks] = *(const bh8*)&qp[(size_t)(qw + g * 16 + ml) * 64 + ks * 32 + quad * 8];

  f4 oacc[2][4], liacc[2];
#pragma unroll
  for (int g = 0; g < 2; ++g) {
#pragma unroll
    for (int j = 0; j < 4; ++j) oacc[g][j] = fzero;
    liacc[g] = fzero;
  }

  // staging: 512 threads cover 64 rows x 8 chunks, 1 GLD16 each for K and V
  const int srow = tid >> 3, scc = tid & 7;       // srow in [0,64)
  const int scg = scc ^ (srow & 7);
  u16* pq = &Pq[wave][ml * 64];   // this lane's 128B region: 16 slots x 8B

  // prologue: stage K+V tile 0 into buffer 0
  GLD16(kp + (size_t)srow * 64 + scg * 8, &Ks[0][(srow * 8 + scc) * 8]);
  GLD16(vp + (size_t)srow * 2048 + scg * 8, &Vs[0][(srow * 8 + scc) * 8]);
  __syncthreads();

  int cur = 0;
#pragma unroll 1
  for (int t = 0; t < 32; ++t) {
    // stage next K+V tile into the other buffer (in flight until end-of-tile drain)
    if (t < 31) {
      int ktn = (t + 1) * 64;
      GLD16(kp + (size_t)(ktn + srow) * 64 + scg * 8, &Ks[cur ^ 1][(srow * 8 + scc) * 8]);
      GLD16(vp + (size_t)srow * 2048 + ktn + scg * 8, &Vs[cur ^ 1][(srow * 8 + scc) * 8]);
    }

    // S^T = K @ Q^T from LDS: s[g][j][r] = S[q=qw+g*16+ml][kt + 16j + 4quad + r]
    f4 s[2][4];
#pragma unroll
    for (int g = 0; g < 2; ++g)
#pragma unroll
      for (int j = 0; j < 4; ++j) s[g][j] = fzero;
#pragma unroll
    for (int ks = 0; ks < 2; ++ks) {
      int cs = (ks * 4 + quad) ^ mlx;
      bh8 kf[4];
#pragma unroll
      for (int j = 0; j < 4; ++j)
        kf[j] = *(const bh8*)(&Ks[cur][((j * 16 + ml) * 8 + cs) * 8]);
      SETPRIO(1);
#pragma unroll
      for (int j = 0; j < 4; ++j) {
        s[0][j] = __builtin_amdgcn_mfma_f32_16x16x32_bf16(kf[j], qf[0][ks], s[0][j], 0, 0, 0);
        s[1][j] = __builtin_amdgcn_mfma_f32_16x16x32_bf16(kf[j], qf[1][ks], s[1][j], 0, 0, 0);
      }
      SETPRIO(0);
    }

    // two ks-phases: softmax keys [32ks,32ks+32) -> write -> pf read -> PV + li.
    // Pq slots reused across phases (same-wave DS in-order => WAR safe).
#pragma unroll
    for (int ks = 0; ks < 2; ++ks) {
      // p = exp2(s) -> bf16 half-up; pack via v_perm byte-extract (bit-identical)
#pragma unroll
      for (int g = 0; g < 2; ++g) {
#pragma unroll
        for (int jl = 0; jl < 2; ++jl) {
          int j = ks * 2 + jl;
          uint32_t w[4];
#pragma unroll
          for (int r = 0; r < 4; ++r) {
            union { float f; uint32_t u; } c;
            c.f = fast_exp2(s[g][j][r]);
            w[r] = c.u + 0x8000u;
          }
          uint2 pk;
          pk.x = pack_hi16(w[0], w[1]);
          pk.y = pack_hi16(w[2], w[3]);
          // slot: bit0 <- quad&1, bit1 <- quad>>1 (pair-distinction lives in bit1)
          int sl = (g * 8 + jl * 4 + 2 * (quad & 1) + (quad >> 1)) ^ ml;
          *(uint2*)(pq + (sl << 2)) = pk;
        }
      }

      // O^T += V^T @ P^T ; li += 1 @ P^T  (vf from LDS, reused for both groups;
      // pf via two b64 reads 16B apart -> unmergeable, conflict-free)
      int cs = (ks * 4 + quad) ^ mlx;
      bh8 vf[4];
#pragma unroll
      for (int j = 0; j < 4; ++j)
        vf[j] = *(const bh8*)(&Vs[cur][((j * 16 + ml) * 8 + cs) * 8]);
#pragma unroll
      for (int g = 0; g < 2; ++g) {
        int slo = (g * 8 + 4 * (quad >> 1) + (quad & 1)) ^ ml;
        int shi = slo ^ 2;
        uint2 lo = *(const uint2*)(pq + (slo << 2));
        uint2 hi = *(const uint2*)(pq + (shi << 2));
        union { uint32_t u[4]; bh8 v; } pf;
        pf.u[0] = lo.x; pf.u[1] = lo.y; pf.u[2] = hi.x; pf.u[3] = hi.y;
        SETPRIO(1);
#pragma unroll
        for (int j = 0; j < 4; ++j)
          oacc[g][j] = __builtin_amdgcn_mfma_f32_16x16x32_bf16(vf[j], pf.v, oacc[g][j], 0, 0, 0);
        liacc[g] = __builtin_amdgcn_mfma_f32_16x16x32_bf16(ones, pf.v, liacc[g], 0, 0, 0);
        SETPRIO(0);
      }
    }
    __syncthreads();   // drains K/V stage (vmcnt) + all LDS reads of buf[cur]
    cur ^= 1;
  }

  // li[g] came through the same bf16 P as the numerator; every acc row holds the
  // full row-sum for q=qw+g*16+ml (ones x P^T), so no cross-lane reduction needed.
#pragma unroll
  for (int g = 0; g < 2; ++g) {
    float inv = 1.0f / liacc[g][0];
    // store o as (b, l, h, d) bf16; lane holds q=qw+g*16+ml, d=16j+4quad+r
    size_t obase = (((size_t)b * 2048 + qw + g * 16 + ml) * 16 + h) * 64;
#pragma unroll
    for (int j = 0; j < 4; ++j) {
      ushort4 w;
      w.x = f2bf(oacc[g][j][0] * inv);
      w.y = f2bf(oacc[g][j][1] * inv);
      w.z = f2bf(oacc[g][j][2] * inv);
      w.w = f2bf(oacc[g][j][3] * inv);
      *(ushort4*)(o + obase + j * 16 + quad * 4) = w;
    }
  }
}

// ---------------- launch ----------------
// prep = merged cvt + weight transposes. gemm_qkv writes vt DIRECTLY into vb
// (transposed); attn (512-thread 8-wave blocks, grid (64,8)) writes o into xb;
// gemm_out64 reads xb. GEMM grids 1-D with in-kernel XCD decomposition.

extern "C" void kernel_launch(void* const* d_in, const int* in_sizes, int n_in,
                              void* d_out, int out_size, void* d_ws, size_t ws_size,
                              hipStream_t stream) {
  const float* x     = (const float*)d_in[0];
  const float* w_qkv = (const float*)d_in[1];
  const float* b_qkv = (const float*)d_in[2];
  const float* w_out = (const float*)d_in[3];
  const float* b_out = (const float*)d_in[4];
  float* out = (float*)d_out;

  u16* ws  = (u16*)d_ws;
  u16* xb  = ws;                                  // 8192*1024 (o reuses after gemm_qkv)
  u16* wqt = xb + (size_t)8192 * 1024;            // 3072*1024
  u16* wot = wqt + (size_t)3072 * 1024;           // 1024*1024
  u16* qb  = wot + (size_t)1024 * 1024;           // 64*2048*64
  u16* kb  = qb + (size_t)64 * 2048 * 64;
  u16* vb  = kb + (size_t)64 * 2048 * 64;         // vt [bh][d][l] (written directly)
  u16* ob  = xb;   // xb dead after gemm_qkv

  prep<<<12288, 256, 0, stream>>>(x, xb, w_qkv, wqt, w_out, wot);
  gemm_qkv<<<1536, 256, 0, stream>>>(xb, wqt, b_qkv, qb, kb, vb);
  attn<<<dim3(64, 8), 512, 0, stream>>>(qb, kb, vb, ob);
  gemm_out64<<<1024, 256, 0, stream>>>(ob, wot, b_out, out);
}